// Round 1
// 132.500 us; speedup vs baseline: 1.0189x; 1.0189x over previous
//
#include <hip/hip_runtime.h>
#include <math.h>

// Problem constants (from reference)
constexpr int   T_PTS  = 4096;
constexpr float LN2    = 0.69314718055994530942f;

// ct = param0 * 5/100 * (RO/KAV) * (1-HLV)/(1-HSV) * (-ln2/TE) * W
// W  = sum_t w_t*log2(cp_t) - (T-1)*log2(T10),  w = [0.5,1,...,1,0.5]

typedef float f32x4 __attribute__((ext_vector_type(4)));

// One WAVE (64 lanes) per row: no LDS, no __syncthreads, 16 float4
// loads in flight per thread (vs 4 in the block-per-row version).
__global__ __launch_bounds__(256) void perfusion_row_reduce(
    const float* __restrict__ param,   // [N,3]
    const float* __restrict__ T10,     // [N,1]
    const float* __restrict__ cp,      // [N,T]
    float* __restrict__ out,           // [N,1]
    int N)
{
    const int wave = threadIdx.x >> 6;          // 0..3
    const int lane = threadIdx.x & 63;
    const int row  = blockIdx.x * 4 + wave;
    if (row >= N) return;

    // Issue the tail-dependency loads early so their latency hides
    // under the 64 MB cp stream.
    const float t10 = T10[row];
    const float p0  = param[row * 3];

    const f32x4* cpv = (const f32x4*)(cp + (size_t)row * T_PTS);

    // 4096 elems / 64 lanes = 64 elems = 16 float4 per lane.
    float s = 0.0f;
    float firstx = 1.0f, lastw = 1.0f;   // only lane 0 / lane 63 values matter
#pragma unroll
    for (int it = 0; it < 16; ++it) {
        f32x4 v = __builtin_nontemporal_load(cpv + it * 64 + lane);
        if (it == 0)  firstx = v.x;      // cp[row][0] lives in lane 0
        if (it == 15) lastw  = v.w;      // cp[row][4095] lives in lane 63
        s += __log2f(v.x) + __log2f(v.y) + __log2f(v.z) + __log2f(v.w);
    }

    // Trapezoid endpoint correction folded into the per-lane partial:
    // subtract half of first+last sample before the reduction.
    if (lane == 0)  s -= 0.5f * __log2f(firstx);
    if (lane == 63) s -= 0.5f * __log2f(lastw);

    // Wave-level butterfly reduction (64 lanes)
#pragma unroll
    for (int off = 32; off > 0; off >>= 1)
        s += __shfl_down(s, off, 64);

    if (lane == 0) {
        // W = sum_t w_t*log2(cp_t) - 4095*log2(T10)
        float W = s - 4095.0f * __log2f(t10);
        float integral = (-LN2 / 32.0f) * W;          // (-1/TE)*ln(...) integrated
        float cbv = p0 * 5.0f;
        float ct = cbv / 100.0f * (1.04f / 1.4f)
                 * ((1.0f - 0.45f) / (1.0f - 0.25f)) * integral;
        out[row] = ct;
    }
}

extern "C" void kernel_launch(void* const* d_in, const int* in_sizes, int n_in,
                              void* d_out, int out_size, void* d_ws, size_t ws_size,
                              hipStream_t stream) {
    const float* param = (const float*)d_in[0];  // [N,3]
    const float* T10   = (const float*)d_in[1];  // [N,1]
    const float* cp    = (const float*)d_in[2];  // [N,T]
    // d_in[3] = raw_s -- unused by the reference; never touched (saves 64 MB of traffic)
    float* out = (float*)d_out;                  // [N,1] float32

    const int N = in_sizes[1];                   // T10 has N elements
    const int blocks = (N + 3) / 4;              // one wave (64 lanes) per row
    perfusion_row_reduce<<<blocks, 256, 0, stream>>>(param, T10, cp, out, N);
}